// Round 1
// baseline (440.164 us; speedup 1.0000x reference)
//
#include <hip/hip_runtime.h>
#include <hip/hip_bf16.h>

typedef __attribute__((ext_vector_type(8))) __bf16 bf16x8;
typedef __attribute__((ext_vector_type(4))) __bf16 bf16x4;
typedef __attribute__((ext_vector_type(4))) float  f32x4;

#define B_    16384
#define N_    32
#define DIN_  128
#define DOUT_ 256

// Pack W (DIN x DOUT, fp32) into bf16 B-fragment order for mfma_f32_16x16x32_bf16.
// Fragment: lane l holds B[k = ks*32 + (l>>4)*8 + j][o = ot*16 + (l&15)], j=0..7.
// Flat layout: wp[(((ks*16)+ot)*64 + l)*8 + j].  4 ks * 16 ot * 64 lanes * 8 = 32768 bf16 = 64KB.
__global__ void prep_w(const float* __restrict__ W, __bf16* __restrict__ wp) {
    int tid = blockIdx.x * 256 + threadIdx.x;   // 0..4095
    int ks = tid >> 10;
    int ot = (tid >> 6) & 15;
    int l  = tid & 63;
    int k0 = ks * 32 + ((l >> 4) << 3);
    int o  = ot * 16 + (l & 15);
    __bf16 v[8];
#pragma unroll
    for (int j = 0; j < 8; ++j) v[j] = (__bf16)W[(size_t)(k0 + j) * DOUT_ + o];
    *reinterpret_cast<bf16x8*>(&wp[(size_t)tid * 8]) = *reinterpret_cast<bf16x8*>(v);
}

__global__ __launch_bounds__(256, 4) void dyr_main(
    const float* __restrict__ embeds, const float* __restrict__ weights,
    const __bf16* __restrict__ wp,    const float* __restrict__ bias,
    float* __restrict__ out)
{
    // LDS: embeds tile in bf16, row-major, stride 136 (128 + 8 pad -> rows stay 16B aligned)
    __shared__ __bf16 elds[32 * 136];   // 8704 B
    __shared__ float  red[4][32];
    __shared__ float  agl[4 * 32];
    __shared__ float  bsh[32];
    __shared__ float  rn[32];
    __shared__ float  sqp[4];

    const int tid = threadIdx.x;
    const int w   = tid >> 6;      // wave 0..3 -> owns output cols [w*64, w*64+64)
    const int l   = tid & 63;
    const int col = l & 15;
    const int q   = l >> 4;        // quad within wave
    const int b   = blockIdx.x;

    // ---- stage embeds[b] (32x128 fp32) -> bf16 LDS ----
    const float4* e4 = reinterpret_cast<const float4*>(embeds + (size_t)b * N_ * DIN_);
#pragma unroll
    for (int p = 0; p < 4; ++p) {
        int fi = p * 256 + tid;            // float4 index, 32 per row
        float4 v = e4[fi];
        int m = fi >> 5;
        int k = (fi & 31) << 2;
        __bf16 pk[4] = { (__bf16)v.x, (__bf16)v.y, (__bf16)v.z, (__bf16)v.w };
        *reinterpret_cast<bf16x4*>(&elds[m * 136 + k]) = *reinterpret_cast<bf16x4*>(pk);
    }
    if (tid < 32) bsh[tid] = weights[(size_t)b * N_ + tid];
    __syncthreads();

    // ---- GEMM: x[n][o] = sum_k e[n][k] * W[k][o], n in 0..32, o in wave's 64 cols ----
    f32x4 acc[2][4];
#pragma unroll
    for (int mt = 0; mt < 2; ++mt)
#pragma unroll
        for (int t = 0; t < 4; ++t) acc[mt][t] = (f32x4){0.f, 0.f, 0.f, 0.f};

    const int aoff0 = col * 136 + (q << 3);   // A-frag: m=col(+16*mt), k=q*8(+32*ks)
#pragma unroll
    for (int ks = 0; ks < 4; ++ks) {
        bf16x8 a0 = *reinterpret_cast<const bf16x8*>(&elds[aoff0 + ks * 32]);
        bf16x8 a1 = *reinterpret_cast<const bf16x8*>(&elds[aoff0 + 16 * 136 + ks * 32]);
#pragma unroll
        for (int t = 0; t < 4; ++t) {
            bf16x8 bf = *reinterpret_cast<const bf16x8*>(
                &wp[((size_t)((ks * 16) + (w * 4 + t)) * 64 + l) * 8]);
            acc[0][t] = __builtin_amdgcn_mfma_f32_16x16x32_bf16(a0, bf, acc[0][t], 0, 0, 0);
            acc[1][t] = __builtin_amdgcn_mfma_f32_16x16x32_bf16(a1, bf, acc[1][t], 0, 0, 0);
        }
    }

    // C/D layout: value = x[n = mt*16 + q*4 + r][o = w*64 + t*16 + col]
    // ---- bias ----
#pragma unroll
    for (int t = 0; t < 4; ++t) {
        float bv = bias[w * 64 + t * 16 + col];
#pragma unroll
        for (int mt = 0; mt < 2; ++mt)
#pragma unroll
            for (int r = 0; r < 4; ++r) acc[mt][t][r] += bv;
    }

    // ---- row norms: nsq[n] = sum_o x^2 ; u_hat = x * rn[n] (kept in acc regs) ----
#pragma unroll
    for (int mt = 0; mt < 2; ++mt)
#pragma unroll
        for (int r = 0; r < 4; ++r) {
            float p = 0.f;
#pragma unroll
            for (int t = 0; t < 4; ++t) p += acc[mt][t][r] * acc[mt][t][r];
            p += __shfl_xor(p, 1); p += __shfl_xor(p, 2);
            p += __shfl_xor(p, 4); p += __shfl_xor(p, 8);
            if (col == 0) red[w][mt * 16 + q * 4 + r] = p;
        }
    __syncthreads();
    if (tid < 32) {
        float nsq = red[0][tid] + red[1][tid] + red[2][tid] + red[3][tid];
        rn[tid] = 1.0f / fmaxf(sqrtf(nsq), 1e-12f);
    }
    __syncthreads();
#pragma unroll
    for (int mt = 0; mt < 2; ++mt)
#pragma unroll
        for (int r = 0; r < 4; ++r) {
            float s = rn[mt * 16 + q * 4 + r];
#pragma unroll
            for (int t = 0; t < 4; ++t) acc[mt][t][r] *= s;
        }

    // ---- dynamic routing ----
    float cme = 0.f;
    float vv[4] = {0.f, 0.f, 0.f, 0.f};
    for (int it = 0; it < 3; ++it) {
        // softmax over n (each 32-lane half computes identically)
        float bval = bsh[l & 31];
        float mx = bval;
        mx = fmaxf(mx, __shfl_xor(mx, 16)); mx = fmaxf(mx, __shfl_xor(mx, 8));
        mx = fmaxf(mx, __shfl_xor(mx, 4));  mx = fmaxf(mx, __shfl_xor(mx, 2));
        mx = fmaxf(mx, __shfl_xor(mx, 1));
        float ex = __expf(bval - mx);
        float sm = ex;
        sm += __shfl_xor(sm, 16); sm += __shfl_xor(sm, 8); sm += __shfl_xor(sm, 4);
        sm += __shfl_xor(sm, 2);  sm += __shfl_xor(sm, 1);
        cme = ex * (32.0f / sm);           // c for n = l&31 lives in lane l

        float cv[2][4];
#pragma unroll
        for (int mt = 0; mt < 2; ++mt)
#pragma unroll
            for (int r = 0; r < 4; ++r) cv[mt][r] = __shfl(cme, mt * 16 + q * 4 + r);

        // s[o] = sum_n c[n]*u[n][o]
        float sv[4];
#pragma unroll
        for (int t = 0; t < 4; ++t) {
            float s = 0.f;
#pragma unroll
            for (int mt = 0; mt < 2; ++mt)
#pragma unroll
                for (int r = 0; r < 4; ++r) s += cv[mt][r] * acc[mt][t][r];
            s += __shfl_xor(s, 16); s += __shfl_xor(s, 32);   // sum the 4 quads
            sv[t] = s;
        }

        // sq = ||s||^2 (wave partial over its 64 cols, then cross-wave via LDS)
        float loc = sv[0]*sv[0] + sv[1]*sv[1] + sv[2]*sv[2] + sv[3]*sv[3];
        loc += __shfl_xor(loc, 1); loc += __shfl_xor(loc, 2);
        loc += __shfl_xor(loc, 4); loc += __shfl_xor(loc, 8);
        if (l == 0) sqp[w] = loc;
        __syncthreads();
        float sq = sqp[0] + sqp[1] + sqp[2] + sqp[3];
        float scale = sq / ((1.0f + sq) * sqrtf(sq + 1e-9f));
#pragma unroll
        for (int t = 0; t < 4; ++t) vv[t] = scale * sv[t];

        if (it < 2) {
            // agree[n] = sum_o u[n][o]*v[o]
#pragma unroll
            for (int mt = 0; mt < 2; ++mt)
#pragma unroll
                for (int r = 0; r < 4; ++r) {
                    float ap = 0.f;
#pragma unroll
                    for (int t = 0; t < 4; ++t) ap += acc[mt][t][r] * vv[t];
                    ap += __shfl_xor(ap, 1); ap += __shfl_xor(ap, 2);
                    ap += __shfl_xor(ap, 4); ap += __shfl_xor(ap, 8);
                    if (col == 0) agl[w * 32 + mt * 16 + q * 4 + r] = ap;
                }
            __syncthreads();
            if (tid < 32) bsh[tid] += agl[tid] + agl[32 + tid] + agl[64 + tid] + agl[96 + tid];
            __syncthreads();
        }
    }

    // ---- outputs: poses (B x 256) then c_out (B x 32), flat-concatenated ----
    if (l < 16) {
#pragma unroll
        for (int t = 0; t < 4; ++t)
            out[(size_t)b * DOUT_ + w * 64 + t * 16 + l] = vv[t];
    }
    if (w == 0 && l < 32)
        out[(size_t)B_ * DOUT_ + (size_t)b * N_ + l] = cme;
}

extern "C" void kernel_launch(void* const* d_in, const int* in_sizes, int n_in,
                              void* d_out, int out_size, void* d_ws, size_t ws_size,
                              hipStream_t stream) {
    const float* embeds  = (const float*)d_in[0];
    const float* weights = (const float*)d_in[1];
    const float* W       = (const float*)d_in[2];
    const float* bias    = (const float*)d_in[3];
    float* out = (float*)d_out;
    __bf16* wp = (__bf16*)d_ws;    // 64 KB of packed bf16 W

    prep_w<<<16, 256, 0, stream>>>(W, wp);
    dyr_main<<<B_, 256, 0, stream>>>(embeds, weights, wp, bias, out);
}